// Round 17
// baseline (2231.479 us; speedup 1.0000x reference)
//
#include <hip/hip_runtime.h>
#include <hip/hip_bf16.h>

typedef unsigned int uint;
typedef unsigned short ushort;

typedef short s16x8 __attribute__((ext_vector_type(8)));
typedef ushort u16x4 __attribute__((ext_vector_type(4)));
typedef float f32x4 __attribute__((ext_vector_type(4)));
typedef uint  u32x4 __attribute__((ext_vector_type(4)));

#define NB 8
#define NT 1024
#define NV 8192
#define ND 768
#define NH 12
#define NL 6
#define NDH 64
#define NFF 3072
#define NTOK (NB*NT)

__device__ __forceinline__ ushort f2bf(float f) {
  uint x = __float_as_uint(f);
  x += 0x7FFFu + ((x >> 16) & 1u);
  return (ushort)(x >> 16);
}
__device__ __forceinline__ float bf2f(ushort u) {
  return __uint_as_float(((uint)u) << 16);
}

// XOR swizzle within a 64-ushort (128B) row: 16B chunk index ^= row&7
__device__ __forceinline__ int swz(int row, int col) {
  return row * 64 + ((((col >> 3) ^ row) & 7) << 3) + (col & 7);
}

// async global->LDS, 16B per lane, dest = wave-uniform base + lane*16
__device__ __forceinline__ void gload16(const ushort* g, ushort* l) {
  __builtin_amdgcn_global_load_lds(
      (const __attribute__((address_space(1))) void*)g,
      (__attribute__((address_space(3))) void*)l, 16, 0, 0);
}

// ---------------- embed (bf16 out) ----------------
__global__ __launch_bounds__(192) void embed_kernel(
    const int* __restrict__ idx, const float* __restrict__ tok,
    const float* __restrict__ pos, ushort* __restrict__ x)
{
  int n = blockIdx.x, t = threadIdx.x;
  int token = idx[n];
  const float4* tp = (const float4*)(tok + (size_t)token * ND);
  const float4* pp = (const float4*)(pos + (size_t)(n & (NT - 1)) * ND);
  float4 a = tp[t], b = pp[t];
  u16x4 r;
  r.x = f2bf(a.x + b.x); r.y = f2bf(a.y + b.y);
  r.z = f2bf(a.z + b.z); r.w = f2bf(a.w + b.w);
  *(u16x4*)&x[(size_t)n * ND + t * 4] = r;
}

// ---------------- layernorm (bf16 in -> bf16 out), 192 thr, 4 elem/thr ------
__global__ __launch_bounds__(192) void ln_kernel(
    const ushort* __restrict__ x, const float* __restrict__ g,
    const float* __restrict__ b, ushort* __restrict__ out)
{
  int row = blockIdx.x, tid = threadIdx.x;
  const ushort* xr = x + (size_t)row * ND;
  u16x4 xv = *(const u16x4*)&xr[tid * 4];
  float v0 = bf2f(xv.x), v1 = bf2f(xv.y), v2 = bf2f(xv.z), v3 = bf2f(xv.w);
  float s = v0 + v1 + v2 + v3;
  float q = v0 * v0 + v1 * v1 + v2 * v2 + v3 * v3;
  #pragma unroll
  for (int d = 1; d < 64; d <<= 1) { s += __shfl_xor(s, d); q += __shfl_xor(q, d); }
  __shared__ float rs[3], rq[3];
  int w = tid >> 6;
  if ((tid & 63) == 0) { rs[w] = s; rq[w] = q; }
  __syncthreads();
  s = rs[0] + rs[1] + rs[2];
  q = rq[0] + rq[1] + rq[2];
  float mean = s * (1.0f / ND);
  float inv = rsqrtf(q * (1.0f / ND) - mean * mean + 1e-5f);
  float4 gv = *(const float4*)&g[tid * 4];
  float4 bv = *(const float4*)&b[tid * 4];
  u16x4 o;
  o.x = f2bf((v0 - mean) * inv * gv.x + bv.x);
  o.y = f2bf((v1 - mean) * inv * gv.y + bv.y);
  o.z = f2bf((v2 - mean) * inv * gv.z + bv.z);
  o.w = f2bf((v3 - mean) * inv * gv.w + bv.w);
  *(u16x4*)&out[(size_t)row * ND + tid * 4] = o;
}

// ------- LDS-tiled transpose body (coalesced both sides) --------------------
__device__ __forceinline__ void transp_body(
    ushort (*t)[72], const float* __restrict__ in, ushort* __restrict__ out,
    int R, int C, int HB, size_t sh, size_t sl, int bid)
{
  const int tid = threadIdx.x;
  int ntx = C >> 6, nty = R >> 6;
  int tpb = ntx * nty;
  int bi = bid / tpb;
  int rem = bid - bi * tpb;
  int ty = rem / ntx, tx = rem - ty * ntx;
  int r0 = ty << 6, c0 = tx << 6;
  const float* ip = in + (size_t)bi * R * C;
  #pragma unroll
  for (int p = 0; p < 4; ++p) {
    int r = (tid >> 4) + p * 16;
    int c = (tid & 15) * 4;
    float4 v = *(const float4*)&ip[(size_t)(r0 + r) * C + c0 + c];
    t[c + 0][r] = f2bf(v.x); t[c + 1][r] = f2bf(v.y);
    t[c + 2][r] = f2bf(v.z); t[c + 3][r] = f2bf(v.w);
  }
  __syncthreads();
  ushort* op = out + (size_t)(bi / HB) * sl + (size_t)(bi % HB) * sh;
  #pragma unroll
  for (int p = 0; p < 4; ++p) {
    int c = (tid >> 4) + p * 16;
    int r = (tid & 15) * 4;
    u16x4 o = *(const u16x4*)&t[c][r];
    *(u16x4*)&op[(size_t)(c0 + c) * R + r0 + r] = o;
  }
}

// ------- all weight transposes in ONE launch (11904 blocks) -----------------
__global__ __launch_bounds__(256) void transp_all(
    const float* __restrict__ Wq, const float* __restrict__ Wk,
    const float* __restrict__ Wv, const float* __restrict__ Wp,
    const float* __restrict__ W1, const float* __restrict__ W2,
    const float* __restrict__ Wlm,
    ushort* __restrict__ qkvT, ushort* __restrict__ wpT,
    ushort* __restrict__ w1T, ushort* __restrict__ w2T,
    ushort* __restrict__ wlmT)
{
  __shared__ ushort t[64][72];
  const size_t LQKV = (size_t)2304 * ND;
  const size_t SH = (size_t)NDH * ND;
  int bid = blockIdx.x;
  if (bid < 864)        transp_body(t, Wq, qkvT,                    ND, NDH, NH, SH, LQKV, bid);
  else if (bid < 1728)  transp_body(t, Wk, qkvT + (size_t)ND*ND,    ND, NDH, NH, SH, LQKV, bid - 864);
  else if (bid < 2592)  transp_body(t, Wv, qkvT + (size_t)2*ND*ND,  ND, NDH, NH, SH, LQKV, bid - 1728);
  else if (bid < 3456)  transp_body(t, Wp, wpT, ND, ND, 1, 0, (size_t)ND * ND, bid - 2592);
  else if (bid < 6912)  transp_body(t, W1, w1T, ND, NFF, 1, 0, (size_t)ND * NFF, bid - 3456);
  else if (bid < 10368) transp_body(t, W2, w2T, NFF, ND, 1, 0, (size_t)ND * NFF, bid - 6912);
  else                  transp_body(t, Wlm, wlmT, ND, NV, 1, 0, (size_t)ND * NV, bid - 10368);
}

// ---------------- bf16 MFMA GEMM 128x128, BK=64 (m97 structure) -------------
// OUT: 0 = none, 1 = bf16, 2 = f32 + LSE partials (outp2 = float2 pstat),
//      3 = qkv-fused (V cols (n0>=1536) -> outp2 = vT transposed store).
template<bool BIAS, bool RELU, bool RESID, int OUT>
__global__ __launch_bounds__(256) void gemm_bt(
    const ushort* __restrict__ A, const ushort* __restrict__ Bt,
    const float* __restrict__ bias, ushort* __restrict__ xres,
    void* __restrict__ outp, void* __restrict__ outp2,
    int M, int N, int K)
{
  __shared__ ushort As[8192];   // [128][64] ushort = 16 KB
  __shared__ ushort Bs[8192];
  const int tid = threadIdx.x;
  const int lane = tid & 63;
  const int w = tid >> 6;
  const int wr = w >> 1, wc = w & 1;
  const int lg = lane >> 4, li = lane & 15;
  const int m0 = blockIdx.y * 128, n0 = blockIdx.x * 128;

  const int tr = tid >> 3;
  const int tc = ((tid & 7) ^ (tr & 7)) << 3;
  const ushort* gA = &A[(size_t)(m0 + tr) * K + tc];
  const ushort* gB = &Bt[(size_t)(n0 + tr) * K + tc];

  f32x4 acc[4][4];
  #pragma unroll
  for (int i = 0; i < 4; ++i)
    #pragma unroll
    for (int j = 0; j < 4; ++j) { f32x4 z = {0.f,0.f,0.f,0.f}; acc[i][j] = z; }

  for (int kk = 0; kk < K; kk += 64) {
    __syncthreads();
    #pragma unroll
    for (int g = 0; g < 4; ++g) {
      gload16(gA + (size_t)(g * 32) * K + kk, &As[g * 2048 + w * 512]);
      gload16(gB + (size_t)(g * 32) * K + kk, &Bs[g * 2048 + w * 512]);
    }
    __syncthreads();
    #pragma unroll
    for (int kh = 0; kh < 2; ++kh) {
      s16x8 af[4], bfr[4];
      #pragma unroll
      for (int i = 0; i < 4; ++i) {
        int ra = wr * 64 + i * 16 + li;
        int rb = wc * 64 + i * 16 + li;
        int cha = (((kh * 4 + lg) ^ (ra & 7)) << 3);
        int chb = (((kh * 4 + lg) ^ (rb & 7)) << 3);
        af[i]  = *(const s16x8*)&As[ra * 64 + cha];
        bfr[i] = *(const s16x8*)&Bs[rb * 64 + chb];
      }
      #pragma unroll
      for (int i = 0; i < 4; ++i)
        #pragma unroll
        for (int j = 0; j < 4; ++j)
          acc[i][j] = __builtin_amdgcn_mfma_f32_16x16x32_bf16(af[i], bfr[j], acc[i][j], 0, 0, 0);
    }
  }

  const bool isV = (OUT == 3) && (n0 >= 1536);   // qkv: blocks 12..17 are V
  #pragma unroll
  for (int i = 0; i < 4; ++i) {
    #pragma unroll
    for (int j = 0; j < 4; ++j) {
      int row0 = m0 + wr * 64 + i * 16 + lg * 4;
      int col  = n0 + wc * 64 + j * 16 + li;
      float bv = BIAS ? bias[col] : 0.f;
      if (isV) {
        int dhg = col - 1536;
        int hh = dhg >> 6, dh = dhg & 63;
        int b_ = row0 >> 10, t0 = row0 & (NT - 1);
        u16x4 o;
        o.x = f2bf(acc[i][j][0]); o.y = f2bf(acc[i][j][1]);
        o.z = f2bf(acc[i][j][2]); o.w = f2bf(acc[i][j][3]);
        *(u16x4*)&((ushort*)outp2)[((size_t)(b_ * NH + hh) * 64 + dh) * NT + t0] = o;
      } else {
        #pragma unroll
        for (int ii = 0; ii < 4; ++ii) {
          float val = acc[i][j][ii] + bv;
          if (RELU) val = fmaxf(val, 0.f);
          size_t off = (size_t)(row0 + ii) * N + col;
          if (RESID) { val += bf2f(xres[off]); xres[off] = f2bf(val); }
          if (OUT == 1 || OUT == 3) ((ushort*)outp)[off] = f2bf(val);
          if (OUT == 2) { ((float*)outp)[off] = val; acc[i][j][ii] = val; }
        }
      }
    }
  }

  if (OUT == 2) {
    // per-row LSE partials over this wave's 64-col half: pstat[row][n0/64 + wc]
    float2* pstat = (float2*)outp2;
    #pragma unroll
    for (int i = 0; i < 4; ++i) {
      #pragma unroll
      for (int ii = 0; ii < 4; ++ii) {
        float mx = acc[i][0][ii];
        #pragma unroll
        for (int j = 1; j < 4; ++j) mx = fmaxf(mx, acc[i][j][ii]);
        #pragma unroll
        for (int d = 1; d < 16; d <<= 1) mx = fmaxf(mx, __shfl_xor(mx, d));
        float se = 0.f;
        #pragma unroll
        for (int j = 0; j < 4; ++j) se += __expf(acc[i][j][ii] - mx);
        #pragma unroll
        for (int d = 1; d < 16; d <<= 1) se += __shfl_xor(se, d);
        if (li == 0) {
          int r = m0 + wr * 64 + i * 16 + lg * 4 + ii;
          float2 v; v.x = mx; v.y = se;
          pstat[(size_t)r * 128 + (n0 >> 6) + wc] = v;
        }
      }
    }
  }
}

// ---------------- MFMA causal flash attention, 128-row q-tiles ---------------
// qkv: [NTOK][2304] bf16 (Q/K valid); vT: [(b*NH+h)*64+dh][NT].
__global__ __launch_bounds__(256) void attn_kernel(
    const ushort* __restrict__ qkv, const ushort* __restrict__ vT,
    ushort* __restrict__ o)
{
  __shared__ ushort Ks[64 * 64];      // [key][dh], swizzled
  __shared__ ushort Vt[64 * 64];      // [dh][key], swizzled
  __shared__ ushort Ps[4][32 * 64];   // per-wave P [qrow 0..31][key], swizzled

  const int tid = threadIdx.x;
  const int lane = tid & 63;
  const int w = tid >> 6;
  const int lg = lane >> 4;
  const int li = lane & 15;

  int bid = blockIdx.x;
  const int qt = bid & 7;
  const int h = (bid >> 3) % NH;
  const int b = bid / (8 * NH);
  const int q0 = qt * 128 + w * 32;
  const size_t nbase = (size_t)b * NT;
  const int hq = h * NDH;
  const int hk = ND + h * NDH;

  s16x8 aq[2][2];
  #pragma unroll
  for (int f = 0; f < 2; ++f)
    #pragma unroll
    for (int c = 0; c < 2; ++c)
      aq[f][c] = *(const s16x8*)&qkv[(nbase + q0 + f * 16 + li) * (3 * ND) + hq + c * 32 + lg * 8];

  float m_r[2][4], l_r[2][4];
  f32x4 oacc[2][4];
  #pragma unroll
  for (int f = 0; f < 2; ++f)
    #pragma unroll
    for (int i = 0; i < 4; ++i) { m_r[f][i] = -1e30f; l_r[f][i] = 0.f; }
  #pragma unroll
  for (int f = 0; f < 2; ++f)
    #pragma unroll
    for (int n = 0; n < 4; ++n) { f32x4 z = {0.f,0.f,0.f,0.f}; oacc[f][n] = z; }

  const float scale = 0.036084391824351615f;  // 768^-0.5 (reference uses D, not DH)
  const ushort* vTb = vT + (size_t)(b * NH + h) * 64 * NT;

  const int nkc = 2 * qt + 2;
  for (int kc = 0; kc < nkc; ++kc) {
    {
      const int kr = lane >> 3;
      const int ch = lane & 7;
      #pragma unroll
      for (int g = 0; g < 2; ++g) {
        int row = g * 32 + w * 8 + kr;   // key for K, dh for Vt
        gload16(&qkv[(nbase + kc * 64 + row) * (size_t)(3 * ND) + hk + ((ch ^ (row & 7)) << 3)],
                &Ks[(g * 32 + w * 8) * 64]);
        gload16(&vTb[(size_t)row * NT + kc * 64 + ((ch ^ (row & 7)) << 3)],
                &Vt[(g * 32 + w * 8) * 64]);
      }
    }
    __syncthreads();
    if (kc * 64 <= q0 + 31) {
      f32x4 s[2][4];
      #pragma unroll
      for (int kt = 0; kt < 4; ++kt) {
        s16x8 bk[2];
        #pragma unroll
        for (int c = 0; c < 2; ++c)
          bk[c] = *(const s16x8*)&Ks[swz(kt * 16 + li, c * 32 + lg * 8)];
        #pragma unroll
        for (int f = 0; f < 2; ++f) {
          f32x4 z = {0.f,0.f,0.f,0.f}; s[f][kt] = z;
          #pragma unroll
          for (int c = 0; c < 2; ++c)
            s[f][kt] = __builtin_amdgcn_mfma_f32_16x16x32_bf16(aq[f][c], bk[c], s[f][kt], 0, 0, 0);
        }
      }
      #pragma unroll
      for (int f = 0; f < 2; ++f) {
        #pragma unroll
        for (int i = 0; i < 4; ++i) {
          int row = q0 + f * 16 + lg * 4 + i;
          float sv[4]; float mx = -1e30f;
          #pragma unroll
          for (int kt = 0; kt < 4; ++kt) {
            int key = kc * 64 + kt * 16 + li;
            float t = s[f][kt][i] * scale;
            t = (key <= row) ? t : -1e30f;
            sv[kt] = t; mx = fmaxf(mx, t);
          }
          #pragma unroll
          for (int d = 1; d < 16; d <<= 1) mx = fmaxf(mx, __shfl_xor(mx, d));
          float mnew = fmaxf(m_r[f][i], mx);
          float corr = __expf(m_r[f][i] - mnew);
          float ps = 0.f;
          #pragma unroll
          for (int kt = 0; kt < 4; ++kt) {
            float pe = __expf(sv[kt] - mnew);
            ps += pe;
            Ps[w][swz(f * 16 + lg * 4 + i, kt * 16 + li)] = f2bf(pe);
          }
          #pragma unroll
          for (int d = 1; d < 16; d <<= 1) ps += __shfl_xor(ps, d);
          l_r[f][i] = l_r[f][i] * corr + ps;
          m_r[f][i] = mnew;
          #pragma unroll
          for (int n = 0; n < 4; ++n) oacc[f][n][i] *= corr;
        }
      }
      #pragma unroll
      for (int c = 0; c < 2; ++c) {
        s16x8 ap[2], bv[4];
        #pragma unroll
        for (int f = 0; f < 2; ++f)
          ap[f] = *(const s16x8*)&Ps[w][swz(f * 16 + li, c * 32 + lg * 8)];
        #pragma unroll
        for (int n = 0; n < 4; ++n)
          bv[n] = *(const s16x8*)&Vt[swz(n * 16 + li, c * 32 + lg * 8)];
        #pragma unroll
        for (int f = 0; f < 2; ++f)
          #pragma unroll
          for (int n = 0; n < 4; ++n)
            oacc[f][n] = __builtin_amdgcn_mfma_f32_16x16x32_bf16(ap[f], bv[n], oacc[f][n], 0, 0, 0);
      }
    }
    __syncthreads();
  }
  #pragma unroll
  for (int f = 0; f < 2; ++f)
    #pragma unroll
    for (int n = 0; n < 4; ++n)
      #pragma unroll
      for (int i = 0; i < 4; ++i) {
        float val = oacc[f][n][i] / l_r[f][i];
        o[(nbase + q0 + f * 16 + lg * 4 + i) * ND + hq + n * 16 + li] = f2bf(val);
      }
}

// ---------------- loss from LSE partials (reads 8 MB, not 268 MB) -----------
__global__ __launch_bounds__(128) void loss_lse(
    const float2* __restrict__ pstat, const float* __restrict__ logits,
    const int* __restrict__ targets, float* __restrict__ rowloss)
{
  int row = blockIdx.x, tid = threadIdx.x;
  float2 p = pstat[(size_t)row * 128 + tid];
  float mx = p.x;
  #pragma unroll
  for (int d = 1; d < 64; d <<= 1) mx = fmaxf(mx, __shfl_xor(mx, d));
  __shared__ float sm[2], ss[2];
  int w = tid >> 6;
  if ((tid & 63) == 0) sm[w] = mx;
  __syncthreads();
  mx = fmaxf(sm[0], sm[1]);
  float se = p.y * __expf(p.x - mx);
  #pragma unroll
  for (int d = 1; d < 64; d <<= 1) se += __shfl_xor(se, d);
  if ((tid & 63) == 0) ss[w] = se;
  __syncthreads();
  if (tid == 0) {
    float lse = mx + __logf(ss[0] + ss[1]);
    rowloss[row] = lse - logits[(size_t)row * NV + targets[row]];
  }
}

__global__ __launch_bounds__(256) void loss_reduce(
    const float* __restrict__ rowloss, float* __restrict__ out_loss)
{
  int tid = threadIdx.x;
  float s = 0.f;
  #pragma unroll
  for (int i = 0; i < 32; ++i) s += rowloss[tid + i * 256];
  #pragma unroll
  for (int d = 1; d < 64; d <<= 1) s += __shfl_xor(s, d);
  __shared__ float red[4];
  int w = tid >> 6, lane = tid & 63;
  if (lane == 0) red[w] = s;
  __syncthreads();
  if (tid == 0) {
    float total = red[0] + red[1] + red[2] + red[3];
    out_loss[0] = total * (1.0f / NTOK);
  }
}

// ---------------- launch ----------------
extern "C" void kernel_launch(void* const* d_in, const int* in_sizes, int n_in,
                              void* d_out, int out_size, void* d_ws, size_t ws_size,
                              hipStream_t stream)
{
  const int*   idx     = (const int*)d_in[0];
  const int*   targets = (const int*)d_in[1];
  const float* tok     = (const float*)d_in[2];
  const float* pos     = (const float*)d_in[3];
  const float* ln1g    = (const float*)d_in[4];
  const float* ln1b    = (const float*)d_in[5];
  const float* Wq      = (const float*)d_in[6];
  const float* Wk      = (const float*)d_in[7];
  const float* Wv      = (const float*)d_in[8];
  const float* Wp      = (const float*)d_in[9];
  const float* bp      = (const float*)d_in[10];
  const float* ln2g    = (const float*)d_in[11];
  const float* ln2b    = (const float*)d_in[12];
  const float* W1      = (const float*)d_in[13];
  const float* b1      = (const float*)d_in[14];
  const float* W2      = (const float*)d_in[15];
  const float* b2      = (const float*)d_in[16];
  const float* lnfg    = (const float*)d_in[17];
  const float* lnfb    = (const float*)d_in[18];
  const float* Wlm     = (const float*)d_in[19];
  const float* blm     = (const float*)d_in[20];

  // d_out (f32, 268,435,460 B) doubles as scratch; all dead before final GEMM.
  char* ob = (char*)d_out;
  ushort* x    = (ushort*)ob;                               // bf16 [NTOK][ND]
  ushort* qkvb = (ushort*)(ob + 25165824);
  ushort* mid  = (ushort*)(ob + 25165824);
  ushort* qkvT = (ushort*)(ob + 75497472);                  // 6 x [2304][768]
  ushort* wpT  = (ushort*)(ob + 75497472 + 21233664);       // 6 x [768][768]
  ushort* w1T  = (ushort*)(ob + 75497472 + 28311552);       // 6 x [3072][768]
  ushort* w2T  = (ushort*)(ob + 75497472 + 56623104);       // 6 x [768][3072]
  ushort* vTb  = (ushort*)(ob + 160432128);                 // [NB*NH*64][NT] bf16, 12.6 MB
  float* logits = (float*)d_out;

  char* ws = (char*)d_ws;
  size_t off = 0;
  auto alloc = [&](size_t bytes) -> void* {
    void* p = ws + off; off += (bytes + 255) & ~(size_t)255; return p;
  };
  ushort* h    = (ushort*)alloc((size_t)NTOK * ND * 2);     // ln out / attn out
  ushort* wlmT = (ushort*)alloc((size_t)ND * NV * 2);       // read during logits GEMM
  float*  rowloss = (float*)alloc((size_t)NTOK * 4);
  float*  pstat = (float*)alloc((size_t)NTOK * 128 * 8);    // float2 [NTOK][128]

  embed_kernel<<<NTOK, 192, 0, stream>>>(idx, tok, pos, x);

  transp_all<<<11904, 256, 0, stream>>>(Wq, Wk, Wv, Wp, W1, W2, Wlm,
                                        qkvT, wpT, w1T, w2T, wlmT);

  const size_t LQKV = (size_t)2304 * ND;
  dim3 gqkv(2304 / 128, NTOK / 128);   // 18 x 64
  dim3 g768(ND / 128, NTOK / 128);     // 6 x 64
  dim3 gff(NFF / 128, NTOK / 128);     // 24 x 64
  dim3 glm(NV / 128, NTOK / 128);      // 64 x 64

  for (int l = 0; l < NL; ++l) {
    ln_kernel<<<NTOK, 192, 0, stream>>>(x, ln1g + l * ND, ln1b + l * ND, h);
    gemm_bt<false,false,false,3><<<gqkv, 256, 0, stream>>>(h, qkvT + l * LQKV, nullptr, nullptr, qkvb, vTb, NTOK, 2304, ND);
    attn_kernel<<<NB * NH * (NT / 128), 256, 0, stream>>>(qkvb, vTb, h);
    gemm_bt<true,false,true,0><<<g768, 256, 0, stream>>>(h, wpT + (size_t)l * ND * ND, bp + l * ND, x, nullptr, nullptr, NTOK, ND, ND);
    ln_kernel<<<NTOK, 192, 0, stream>>>(x, ln2g + l * ND, ln2b + l * ND, h);
    gemm_bt<true,true,false,1><<<gff, 256, 0, stream>>>(h, w1T + (size_t)l * ND * NFF, b1 + (size_t)l * NFF, nullptr, mid, nullptr, NTOK, NFF, ND);
    gemm_bt<true,false,true,0><<<g768, 256, 0, stream>>>(mid, w2T + (size_t)l * ND * NFF, b2 + l * ND, x, nullptr, nullptr, NTOK, ND, NFF);
  }

  ln_kernel<<<NTOK, 192, 0, stream>>>(x, lnfg, lnfb, h);
  gemm_bt<true,false,false,2><<<glm, 256, 0, stream>>>(h, wlmT, blm, nullptr, logits, pstat, NTOK, NV, ND);

  loss_lse<<<NTOK, 128, 0, stream>>>((const float2*)pstat, logits, targets, rowloss);
  loss_reduce<<<1, 256, 0, stream>>>(rowloss, logits + (size_t)NTOK * NV);
}

// Round 18
// 2201.930 us; speedup vs baseline: 1.0134x; 1.0134x over previous
//
#include <hip/hip_runtime.h>
#include <hip/hip_bf16.h>

typedef unsigned int uint;
typedef unsigned short ushort;

typedef short s16x8 __attribute__((ext_vector_type(8)));
typedef ushort u16x4 __attribute__((ext_vector_type(4)));
typedef float f32x4 __attribute__((ext_vector_type(4)));
typedef uint  u32x4 __attribute__((ext_vector_type(4)));

#define NB 8
#define NT 1024
#define NV 8192
#define ND 768
#define NH 12
#define NL 6
#define NDH 64
#define NFF 3072
#define NTOK (NB*NT)

__device__ __forceinline__ ushort f2bf(float f) {
  uint x = __float_as_uint(f);
  x += 0x7FFFu + ((x >> 16) & 1u);
  return (ushort)(x >> 16);
}
__device__ __forceinline__ float bf2f(ushort u) {
  return __uint_as_float(((uint)u) << 16);
}

// XOR swizzle within a 64-ushort (128B) row: 16B chunk index ^= row&7
__device__ __forceinline__ int swz(int row, int col) {
  return row * 64 + ((((col >> 3) ^ row) & 7) << 3) + (col & 7);
}

// async global->LDS, 16B per lane, dest = wave-uniform base + lane*16
__device__ __forceinline__ void gload16(const ushort* g, ushort* l) {
  __builtin_amdgcn_global_load_lds(
      (const __attribute__((address_space(1))) void*)g,
      (__attribute__((address_space(3))) void*)l, 16, 0, 0);
}

// ---------------- embed (bf16 out) ----------------
__global__ __launch_bounds__(192) void embed_kernel(
    const int* __restrict__ idx, const float* __restrict__ tok,
    const float* __restrict__ pos, ushort* __restrict__ x)
{
  int n = blockIdx.x, t = threadIdx.x;
  int token = idx[n];
  const float4* tp = (const float4*)(tok + (size_t)token * ND);
  const float4* pp = (const float4*)(pos + (size_t)(n & (NT - 1)) * ND);
  float4 a = tp[t], b = pp[t];
  u16x4 r;
  r.x = f2bf(a.x + b.x); r.y = f2bf(a.y + b.y);
  r.z = f2bf(a.z + b.z); r.w = f2bf(a.w + b.w);
  *(u16x4*)&x[(size_t)n * ND + t * 4] = r;
}

// ---------------- layernorm (bf16 in -> bf16 out), 192 thr, 4 elem/thr ------
__global__ __launch_bounds__(192) void ln_kernel(
    const ushort* __restrict__ x, const float* __restrict__ g,
    const float* __restrict__ b, ushort* __restrict__ out)
{
  int row = blockIdx.x, tid = threadIdx.x;
  const ushort* xr = x + (size_t)row * ND;
  u16x4 xv = *(const u16x4*)&xr[tid * 4];
  float v0 = bf2f(xv.x), v1 = bf2f(xv.y), v2 = bf2f(xv.z), v3 = bf2f(xv.w);
  float s = v0 + v1 + v2 + v3;
  float q = v0 * v0 + v1 * v1 + v2 * v2 + v3 * v3;
  #pragma unroll
  for (int d = 1; d < 64; d <<= 1) { s += __shfl_xor(s, d); q += __shfl_xor(q, d); }
  __shared__ float rs[3], rq[3];
  int w = tid >> 6;
  if ((tid & 63) == 0) { rs[w] = s; rq[w] = q; }
  __syncthreads();
  s = rs[0] + rs[1] + rs[2];
  q = rq[0] + rq[1] + rq[2];
  float mean = s * (1.0f / ND);
  float inv = rsqrtf(q * (1.0f / ND) - mean * mean + 1e-5f);
  float4 gv = *(const float4*)&g[tid * 4];
  float4 bv = *(const float4*)&b[tid * 4];
  u16x4 o;
  o.x = f2bf((v0 - mean) * inv * gv.x + bv.x);
  o.y = f2bf((v1 - mean) * inv * gv.y + bv.y);
  o.z = f2bf((v2 - mean) * inv * gv.z + bv.z);
  o.w = f2bf((v3 - mean) * inv * gv.w + bv.w);
  *(u16x4*)&out[(size_t)row * ND + tid * 4] = o;
}

// ------- LDS-tiled transpose body (coalesced both sides) --------------------
__device__ __forceinline__ void transp_body(
    ushort (*t)[72], const float* __restrict__ in, ushort* __restrict__ out,
    int R, int C, int HB, size_t sh, size_t sl, int bid)
{
  const int tid = threadIdx.x;
  int ntx = C >> 6, nty = R >> 6;
  int tpb = ntx * nty;
  int bi = bid / tpb;
  int rem = bid - bi * tpb;
  int ty = rem / ntx, tx = rem - ty * ntx;
  int r0 = ty << 6, c0 = tx << 6;
  const float* ip = in + (size_t)bi * R * C;
  #pragma unroll
  for (int p = 0; p < 4; ++p) {
    int r = (tid >> 4) + p * 16;
    int c = (tid & 15) * 4;
    float4 v = *(const float4*)&ip[(size_t)(r0 + r) * C + c0 + c];
    t[c + 0][r] = f2bf(v.x); t[c + 1][r] = f2bf(v.y);
    t[c + 2][r] = f2bf(v.z); t[c + 3][r] = f2bf(v.w);
  }
  __syncthreads();
  ushort* op = out + (size_t)(bi / HB) * sl + (size_t)(bi % HB) * sh;
  #pragma unroll
  for (int p = 0; p < 4; ++p) {
    int c = (tid >> 4) + p * 16;
    int r = (tid & 15) * 4;
    u16x4 o = *(const u16x4*)&t[c][r];
    *(u16x4*)&op[(size_t)(c0 + c) * R + r0 + r] = o;
  }
}

// ------- all weight transposes in ONE launch (11904 blocks) -----------------
__global__ __launch_bounds__(256) void transp_all(
    const float* __restrict__ Wq, const float* __restrict__ Wk,
    const float* __restrict__ Wv, const float* __restrict__ Wp,
    const float* __restrict__ W1, const float* __restrict__ W2,
    const float* __restrict__ Wlm,
    ushort* __restrict__ qkvT, ushort* __restrict__ wpT,
    ushort* __restrict__ w1T, ushort* __restrict__ w2T,
    ushort* __restrict__ wlmT)
{
  __shared__ ushort t[64][72];
  const size_t LQKV = (size_t)2304 * ND;
  const size_t SH = (size_t)NDH * ND;
  int bid = blockIdx.x;
  if (bid < 864)        transp_body(t, Wq, qkvT,                    ND, NDH, NH, SH, LQKV, bid);
  else if (bid < 1728)  transp_body(t, Wk, qkvT + (size_t)ND*ND,    ND, NDH, NH, SH, LQKV, bid - 864);
  else if (bid < 2592)  transp_body(t, Wv, qkvT + (size_t)2*ND*ND,  ND, NDH, NH, SH, LQKV, bid - 1728);
  else if (bid < 3456)  transp_body(t, Wp, wpT, ND, ND, 1, 0, (size_t)ND * ND, bid - 2592);
  else if (bid < 6912)  transp_body(t, W1, w1T, ND, NFF, 1, 0, (size_t)ND * NFF, bid - 3456);
  else if (bid < 10368) transp_body(t, W2, w2T, NFF, ND, 1, 0, (size_t)ND * NFF, bid - 6912);
  else                  transp_body(t, Wlm, wlmT, ND, NV, 1, 0, (size_t)ND * NV, bid - 10368);
}

// ---------------- bf16 MFMA GEMM 128x128, BK=64 (m97 structure) -------------
// OUT: 0 = none, 1 = bf16, 2 = f32 + LSE partials (outp2 = float2 pstat;
//      single fused epilogue pass, no acc writeback — keeps VGPR <= 96),
//      3 = qkv-fused (V cols (n0>=1536) -> outp2 = vT transposed store).
template<bool BIAS, bool RELU, bool RESID, int OUT>
__global__ __launch_bounds__(256) void gemm_bt(
    const ushort* __restrict__ A, const ushort* __restrict__ Bt,
    const float* __restrict__ bias, ushort* __restrict__ xres,
    void* __restrict__ outp, void* __restrict__ outp2,
    int M, int N, int K)
{
  __shared__ ushort As[8192];   // [128][64] ushort = 16 KB
  __shared__ ushort Bs[8192];
  const int tid = threadIdx.x;
  const int lane = tid & 63;
  const int w = tid >> 6;
  const int wr = w >> 1, wc = w & 1;
  const int lg = lane >> 4, li = lane & 15;
  const int m0 = blockIdx.y * 128, n0 = blockIdx.x * 128;

  const int tr = tid >> 3;
  const int tc = ((tid & 7) ^ (tr & 7)) << 3;
  const ushort* gA = &A[(size_t)(m0 + tr) * K + tc];
  const ushort* gB = &Bt[(size_t)(n0 + tr) * K + tc];

  f32x4 acc[4][4];
  #pragma unroll
  for (int i = 0; i < 4; ++i)
    #pragma unroll
    for (int j = 0; j < 4; ++j) { f32x4 z = {0.f,0.f,0.f,0.f}; acc[i][j] = z; }

  for (int kk = 0; kk < K; kk += 64) {
    __syncthreads();
    #pragma unroll
    for (int g = 0; g < 4; ++g) {
      gload16(gA + (size_t)(g * 32) * K + kk, &As[g * 2048 + w * 512]);
      gload16(gB + (size_t)(g * 32) * K + kk, &Bs[g * 2048 + w * 512]);
    }
    __syncthreads();
    #pragma unroll
    for (int kh = 0; kh < 2; ++kh) {
      s16x8 af[4], bfr[4];
      #pragma unroll
      for (int i = 0; i < 4; ++i) {
        int ra = wr * 64 + i * 16 + li;
        int rb = wc * 64 + i * 16 + li;
        int cha = (((kh * 4 + lg) ^ (ra & 7)) << 3);
        int chb = (((kh * 4 + lg) ^ (rb & 7)) << 3);
        af[i]  = *(const s16x8*)&As[ra * 64 + cha];
        bfr[i] = *(const s16x8*)&Bs[rb * 64 + chb];
      }
      #pragma unroll
      for (int i = 0; i < 4; ++i)
        #pragma unroll
        for (int j = 0; j < 4; ++j)
          acc[i][j] = __builtin_amdgcn_mfma_f32_16x16x32_bf16(af[i], bfr[j], acc[i][j], 0, 0, 0);
    }
  }

  if (OUT == 2) {
    // fused f32 store + per-row LSE partials, single pass, no acc writeback
    float2* pstat = (float2*)outp2;
    float* op = (float*)outp;
    float bvv[4];
    #pragma unroll
    for (int j = 0; j < 4; ++j)
      bvv[j] = BIAS ? bias[n0 + wc * 64 + j * 16 + li] : 0.f;
    #pragma unroll
    for (int i = 0; i < 4; ++i) {
      #pragma unroll
      for (int ii = 0; ii < 4; ++ii) {
        int row = m0 + wr * 64 + i * 16 + lg * 4 + ii;
        float v4[4];
        float mx = -1e30f;
        #pragma unroll
        for (int j = 0; j < 4; ++j) {
          float val = acc[i][j][ii] + bvv[j];
          op[(size_t)row * N + n0 + wc * 64 + j * 16 + li] = val;
          v4[j] = val; mx = fmaxf(mx, val);
        }
        #pragma unroll
        for (int d = 1; d < 16; d <<= 1) mx = fmaxf(mx, __shfl_xor(mx, d));
        float se = 0.f;
        #pragma unroll
        for (int j = 0; j < 4; ++j) se += __expf(v4[j] - mx);
        #pragma unroll
        for (int d = 1; d < 16; d <<= 1) se += __shfl_xor(se, d);
        if (li == 0) {
          float2 pv; pv.x = mx; pv.y = se;
          pstat[(size_t)row * 128 + (n0 >> 6) + wc] = pv;
        }
      }
    }
    return;
  }

  const bool isV = (OUT == 3) && (n0 >= 1536);   // qkv: blocks 12..17 are V
  #pragma unroll
  for (int i = 0; i < 4; ++i) {
    #pragma unroll
    for (int j = 0; j < 4; ++j) {
      int row0 = m0 + wr * 64 + i * 16 + lg * 4;
      int col  = n0 + wc * 64 + j * 16 + li;
      float bv = BIAS ? bias[col] : 0.f;
      if (isV) {
        int dhg = col - 1536;
        int hh = dhg >> 6, dh = dhg & 63;
        int b_ = row0 >> 10, t0 = row0 & (NT - 1);
        u16x4 o;
        o.x = f2bf(acc[i][j][0]); o.y = f2bf(acc[i][j][1]);
        o.z = f2bf(acc[i][j][2]); o.w = f2bf(acc[i][j][3]);
        *(u16x4*)&((ushort*)outp2)[((size_t)(b_ * NH + hh) * 64 + dh) * NT + t0] = o;
      } else {
        #pragma unroll
        for (int ii = 0; ii < 4; ++ii) {
          float val = acc[i][j][ii] + bv;
          if (RELU) val = fmaxf(val, 0.f);
          size_t off = (size_t)(row0 + ii) * N + col;
          if (RESID) { val += bf2f(xres[off]); xres[off] = f2bf(val); }
          if (OUT == 1 || OUT == 3) ((ushort*)outp)[off] = f2bf(val);
        }
      }
    }
  }
}

// ---------------- MFMA causal flash attention, 128-row q-tiles ---------------
// qkv: [NTOK][2304] bf16 (Q/K valid); vT: [(b*NH+h)*64+dh][NT].
__global__ __launch_bounds__(256) void attn_kernel(
    const ushort* __restrict__ qkv, const ushort* __restrict__ vT,
    ushort* __restrict__ o)
{
  __shared__ ushort Ks[64 * 64];      // [key][dh], swizzled
  __shared__ ushort Vt[64 * 64];      // [dh][key], swizzled
  __shared__ ushort Ps[4][32 * 64];   // per-wave P [qrow 0..31][key], swizzled

  const int tid = threadIdx.x;
  const int lane = tid & 63;
  const int w = tid >> 6;
  const int lg = lane >> 4;
  const int li = lane & 15;

  int bid = blockIdx.x;
  const int qt = bid & 7;
  const int h = (bid >> 3) % NH;
  const int b = bid / (8 * NH);
  const int q0 = qt * 128 + w * 32;
  const size_t nbase = (size_t)b * NT;
  const int hq = h * NDH;
  const int hk = ND + h * NDH;

  s16x8 aq[2][2];
  #pragma unroll
  for (int f = 0; f < 2; ++f)
    #pragma unroll
    for (int c = 0; c < 2; ++c)
      aq[f][c] = *(const s16x8*)&qkv[(nbase + q0 + f * 16 + li) * (3 * ND) + hq + c * 32 + lg * 8];

  float m_r[2][4], l_r[2][4];
  f32x4 oacc[2][4];
  #pragma unroll
  for (int f = 0; f < 2; ++f)
    #pragma unroll
    for (int i = 0; i < 4; ++i) { m_r[f][i] = -1e30f; l_r[f][i] = 0.f; }
  #pragma unroll
  for (int f = 0; f < 2; ++f)
    #pragma unroll
    for (int n = 0; n < 4; ++n) { f32x4 z = {0.f,0.f,0.f,0.f}; oacc[f][n] = z; }

  const float scale = 0.036084391824351615f;  // 768^-0.5 (reference uses D, not DH)
  const ushort* vTb = vT + (size_t)(b * NH + h) * 64 * NT;

  const int nkc = 2 * qt + 2;
  for (int kc = 0; kc < nkc; ++kc) {
    {
      const int kr = lane >> 3;
      const int ch = lane & 7;
      #pragma unroll
      for (int g = 0; g < 2; ++g) {
        int row = g * 32 + w * 8 + kr;   // key for K, dh for Vt
        gload16(&qkv[(nbase + kc * 64 + row) * (size_t)(3 * ND) + hk + ((ch ^ (row & 7)) << 3)],
                &Ks[(g * 32 + w * 8) * 64]);
        gload16(&vTb[(size_t)row * NT + kc * 64 + ((ch ^ (row & 7)) << 3)],
                &Vt[(g * 32 + w * 8) * 64]);
      }
    }
    __syncthreads();
    if (kc * 64 <= q0 + 31) {
      f32x4 s[2][4];
      #pragma unroll
      for (int kt = 0; kt < 4; ++kt) {
        s16x8 bk[2];
        #pragma unroll
        for (int c = 0; c < 2; ++c)
          bk[c] = *(const s16x8*)&Ks[swz(kt * 16 + li, c * 32 + lg * 8)];
        #pragma unroll
        for (int f = 0; f < 2; ++f) {
          f32x4 z = {0.f,0.f,0.f,0.f}; s[f][kt] = z;
          #pragma unroll
          for (int c = 0; c < 2; ++c)
            s[f][kt] = __builtin_amdgcn_mfma_f32_16x16x32_bf16(aq[f][c], bk[c], s[f][kt], 0, 0, 0);
        }
      }
      #pragma unroll
      for (int f = 0; f < 2; ++f) {
        #pragma unroll
        for (int i = 0; i < 4; ++i) {
          int row = q0 + f * 16 + lg * 4 + i;
          float sv[4]; float mx = -1e30f;
          #pragma unroll
          for (int kt = 0; kt < 4; ++kt) {
            int key = kc * 64 + kt * 16 + li;
            float t = s[f][kt][i] * scale;
            t = (key <= row) ? t : -1e30f;
            sv[kt] = t; mx = fmaxf(mx, t);
          }
          #pragma unroll
          for (int d = 1; d < 16; d <<= 1) mx = fmaxf(mx, __shfl_xor(mx, d));
          float mnew = fmaxf(m_r[f][i], mx);
          float corr = __expf(m_r[f][i] - mnew);
          float ps = 0.f;
          #pragma unroll
          for (int kt = 0; kt < 4; ++kt) {
            float pe = __expf(sv[kt] - mnew);
            ps += pe;
            Ps[w][swz(f * 16 + lg * 4 + i, kt * 16 + li)] = f2bf(pe);
          }
          #pragma unroll
          for (int d = 1; d < 16; d <<= 1) ps += __shfl_xor(ps, d);
          l_r[f][i] = l_r[f][i] * corr + ps;
          m_r[f][i] = mnew;
          #pragma unroll
          for (int n = 0; n < 4; ++n) oacc[f][n][i] *= corr;
        }
      }
      #pragma unroll
      for (int c = 0; c < 2; ++c) {
        s16x8 ap[2], bv[4];
        #pragma unroll
        for (int f = 0; f < 2; ++f)
          ap[f] = *(const s16x8*)&Ps[w][swz(f * 16 + li, c * 32 + lg * 8)];
        #pragma unroll
        for (int n = 0; n < 4; ++n)
          bv[n] = *(const s16x8*)&Vt[swz(n * 16 + li, c * 32 + lg * 8)];
        #pragma unroll
        for (int f = 0; f < 2; ++f)
          #pragma unroll
          for (int n = 0; n < 4; ++n)
            oacc[f][n] = __builtin_amdgcn_mfma_f32_16x16x32_bf16(ap[f], bv[n], oacc[f][n], 0, 0, 0);
      }
    }
    __syncthreads();
  }
  #pragma unroll
  for (int f = 0; f < 2; ++f)
    #pragma unroll
    for (int n = 0; n < 4; ++n)
      #pragma unroll
      for (int i = 0; i < 4; ++i) {
        float val = oacc[f][n][i] / l_r[f][i];
        o[(nbase + q0 + f * 16 + lg * 4 + i) * ND + hq + n * 16 + li] = f2bf(val);
      }
}

// ---------------- loss from LSE partials (reads 8 MB, not 268 MB) -----------
__global__ __launch_bounds__(128) void loss_lse(
    const float2* __restrict__ pstat, const float* __restrict__ logits,
    const int* __restrict__ targets, float* __restrict__ rowloss)
{
  int row = blockIdx.x, tid = threadIdx.x;
  float2 p = pstat[(size_t)row * 128 + tid];
  float mx = p.x;
  #pragma unroll
  for (int d = 1; d < 64; d <<= 1) mx = fmaxf(mx, __shfl_xor(mx, d));
  __shared__ float sm[2], ss[2];
  int w = tid >> 6;
  if ((tid & 63) == 0) sm[w] = mx;
  __syncthreads();
  mx = fmaxf(sm[0], sm[1]);
  float se = p.y * __expf(p.x - mx);
  #pragma unroll
  for (int d = 1; d < 64; d <<= 1) se += __shfl_xor(se, d);
  if ((tid & 63) == 0) ss[w] = se;
  __syncthreads();
  if (tid == 0) {
    float lse = mx + __logf(ss[0] + ss[1]);
    rowloss[row] = lse - logits[(size_t)row * NV + targets[row]];
  }
}

__global__ __launch_bounds__(256) void loss_reduce(
    const float* __restrict__ rowloss, float* __restrict__ out_loss)
{
  int tid = threadIdx.x;
  float s = 0.f;
  #pragma unroll
  for (int i = 0; i < 32; ++i) s += rowloss[tid + i * 256];
  #pragma unroll
  for (int d = 1; d < 64; d <<= 1) s += __shfl_xor(s, d);
  __shared__ float red[4];
  int w = tid >> 6, lane = tid & 63;
  if (lane == 0) red[w] = s;
  __syncthreads();
  if (tid == 0) {
    float total = red[0] + red[1] + red[2] + red[3];
    out_loss[0] = total * (1.0f / NTOK);
  }
}

// ---------------- launch ----------------
extern "C" void kernel_launch(void* const* d_in, const int* in_sizes, int n_in,
                              void* d_out, int out_size, void* d_ws, size_t ws_size,
                              hipStream_t stream)
{
  const int*   idx     = (const int*)d_in[0];
  const int*   targets = (const int*)d_in[1];
  const float* tok     = (const float*)d_in[2];
  const float* pos     = (const float*)d_in[3];
  const float* ln1g    = (const float*)d_in[4];
  const float* ln1b    = (const float*)d_in[5];
  const float* Wq      = (const float*)d_in[6];
  const float* Wk      = (const float*)d_in[7];
  const float* Wv      = (const float*)d_in[8];
  const float* Wp      = (const float*)d_in[9];
  const float* bp      = (const float*)d_in[10];
  const float* ln2g    = (const float*)d_in[11];
  const float* ln2b    = (const float*)d_in[12];
  const float* W1      = (const float*)d_in[13];
  const float* b1      = (const float*)d_in[14];
  const float* W2      = (const float*)d_in[15];
  const float* b2      = (const float*)d_in[16];
  const float* lnfg    = (const float*)d_in[17];
  const float* lnfb    = (const float*)d_in[18];
  const float* Wlm     = (const float*)d_in[19];
  const float* blm     = (const float*)d_in[20];

  // d_out (f32, 268,435,460 B) doubles as scratch; all dead before final GEMM.
  char* ob = (char*)d_out;
  ushort* x    = (ushort*)ob;                               // bf16 [NTOK][ND]
  ushort* qkvb = (ushort*)(ob + 25165824);
  ushort* mid  = (ushort*)(ob + 25165824);
  ushort* qkvT = (ushort*)(ob + 75497472);                  // 6 x [2304][768]
  ushort* wpT  = (ushort*)(ob + 75497472 + 21233664);       // 6 x [768][768]
  ushort* w1T  = (ushort*)(ob + 75497472 + 28311552);       // 6 x [3072][768]
  ushort* w2T  = (ushort*)(ob + 75497472 + 56623104);       // 6 x [768][3072]
  ushort* vTb  = (ushort*)(ob + 160432128);                 // [NB*NH*64][NT] bf16, 12.6 MB
  float* logits = (float*)d_out;

  char* ws = (char*)d_ws;
  size_t off = 0;
  auto alloc = [&](size_t bytes) -> void* {
    void* p = ws + off; off += (bytes + 255) & ~(size_t)255; return p;
  };
  ushort* h    = (ushort*)alloc((size_t)NTOK * ND * 2);     // ln out / attn out
  ushort* wlmT = (ushort*)alloc((size_t)ND * NV * 2);       // read during logits GEMM
  float*  rowloss = (float*)alloc((size_t)NTOK * 4);
  float*  pstat = (float*)alloc((size_t)NTOK * 128 * 8);    // float2 [NTOK][128]

  embed_kernel<<<NTOK, 192, 0, stream>>>(idx, tok, pos, x);

  transp_all<<<11904, 256, 0, stream>>>(Wq, Wk, Wv, Wp, W1, W2, Wlm,
                                        qkvT, wpT, w1T, w2T, wlmT);

  const size_t LQKV = (size_t)2304 * ND;
  dim3 gqkv(2304 / 128, NTOK / 128);   // 18 x 64
  dim3 g768(ND / 128, NTOK / 128);     // 6 x 64
  dim3 gff(NFF / 128, NTOK / 128);     // 24 x 64
  dim3 glm(NV / 128, NTOK / 128);      // 64 x 64

  for (int l = 0; l < NL; ++l) {
    ln_kernel<<<NTOK, 192, 0, stream>>>(x, ln1g + l * ND, ln1b + l * ND, h);
    gemm_bt<false,false,false,3><<<gqkv, 256, 0, stream>>>(h, qkvT + l * LQKV, nullptr, nullptr, qkvb, vTb, NTOK, 2304, ND);
    attn_kernel<<<NB * NH * (NT / 128), 256, 0, stream>>>(qkvb, vTb, h);
    gemm_bt<true,false,true,0><<<g768, 256, 0, stream>>>(h, wpT + (size_t)l * ND * ND, bp + l * ND, x, nullptr, nullptr, NTOK, ND, ND);
    ln_kernel<<<NTOK, 192, 0, stream>>>(x, ln2g + l * ND, ln2b + l * ND, h);
    gemm_bt<true,true,false,1><<<gff, 256, 0, stream>>>(h, w1T + (size_t)l * ND * NFF, b1 + (size_t)l * NFF, nullptr, mid, nullptr, NTOK, NFF, ND);
    gemm_bt<true,false,true,0><<<g768, 256, 0, stream>>>(mid, w2T + (size_t)l * ND * NFF, b2 + l * ND, x, nullptr, nullptr, NTOK, ND, NFF);
  }

  ln_kernel<<<NTOK, 192, 0, stream>>>(x, lnfg, lnfb, h);
  gemm_bt<true,false,false,2><<<glm, 256, 0, stream>>>(h, wlmT, blm, nullptr, logits, pstat, NTOK, NV, ND);

  loss_lse<<<NTOK, 128, 0, stream>>>((const float2*)pstat, logits, targets, rowloss);
  loss_reduce<<<1, 256, 0, stream>>>(rowloss, logits + (size_t)NTOK * NV);
}

// Round 19
// 2112.790 us; speedup vs baseline: 1.0562x; 1.0422x over previous
//
#include <hip/hip_runtime.h>
#include <hip/hip_bf16.h>

typedef unsigned int uint;
typedef unsigned short ushort;

typedef short s16x8 __attribute__((ext_vector_type(8)));
typedef ushort u16x4 __attribute__((ext_vector_type(4)));
typedef float f32x4 __attribute__((ext_vector_type(4)));
typedef uint  u32x4 __attribute__((ext_vector_type(4)));

#define NB 8
#define NT 1024
#define NV 8192
#define ND 768
#define NH 12
#define NL 6
#define NDH 64
#define NFF 3072
#define NTOK (NB*NT)

__device__ __forceinline__ ushort f2bf(float f) {
  uint x = __float_as_uint(f);
  x += 0x7FFFu + ((x >> 16) & 1u);
  return (ushort)(x >> 16);
}
__device__ __forceinline__ float bf2f(ushort u) {
  return __uint_as_float(((uint)u) << 16);
}

// XOR swizzle within a 64-ushort (128B) row: 16B chunk index ^= row&7
__device__ __forceinline__ int swz(int row, int col) {
  return row * 64 + ((((col >> 3) ^ row) & 7) << 3) + (col & 7);
}

// async global->LDS, 16B per lane, dest = wave-uniform base + lane*16
__device__ __forceinline__ void gload16(const ushort* g, ushort* l) {
  __builtin_amdgcn_global_load_lds(
      (const __attribute__((address_space(1))) void*)g,
      (__attribute__((address_space(3))) void*)l, 16, 0, 0);
}

// ---------------- embed (bf16 out) ----------------
__global__ __launch_bounds__(192) void embed_kernel(
    const int* __restrict__ idx, const float* __restrict__ tok,
    const float* __restrict__ pos, ushort* __restrict__ x)
{
  int n = blockIdx.x, t = threadIdx.x;
  int token = idx[n];
  const float4* tp = (const float4*)(tok + (size_t)token * ND);
  const float4* pp = (const float4*)(pos + (size_t)(n & (NT - 1)) * ND);
  float4 a = tp[t], b = pp[t];
  u16x4 r;
  r.x = f2bf(a.x + b.x); r.y = f2bf(a.y + b.y);
  r.z = f2bf(a.z + b.z); r.w = f2bf(a.w + b.w);
  *(u16x4*)&x[(size_t)n * ND + t * 4] = r;
}

// ---------------- layernorm (bf16 in -> bf16 out), 192 thr, 4 elem/thr ------
__global__ __launch_bounds__(192) void ln_kernel(
    const ushort* __restrict__ x, const float* __restrict__ g,
    const float* __restrict__ b, ushort* __restrict__ out)
{
  int row = blockIdx.x, tid = threadIdx.x;
  const ushort* xr = x + (size_t)row * ND;
  u16x4 xv = *(const u16x4*)&xr[tid * 4];
  float v0 = bf2f(xv.x), v1 = bf2f(xv.y), v2 = bf2f(xv.z), v3 = bf2f(xv.w);
  float s = v0 + v1 + v2 + v3;
  float q = v0 * v0 + v1 * v1 + v2 * v2 + v3 * v3;
  #pragma unroll
  for (int d = 1; d < 64; d <<= 1) { s += __shfl_xor(s, d); q += __shfl_xor(q, d); }
  __shared__ float rs[3], rq[3];
  int w = tid >> 6;
  if ((tid & 63) == 0) { rs[w] = s; rq[w] = q; }
  __syncthreads();
  s = rs[0] + rs[1] + rs[2];
  q = rq[0] + rq[1] + rq[2];
  float mean = s * (1.0f / ND);
  float inv = rsqrtf(q * (1.0f / ND) - mean * mean + 1e-5f);
  float4 gv = *(const float4*)&g[tid * 4];
  float4 bv = *(const float4*)&b[tid * 4];
  u16x4 o;
  o.x = f2bf((v0 - mean) * inv * gv.x + bv.x);
  o.y = f2bf((v1 - mean) * inv * gv.y + bv.y);
  o.z = f2bf((v2 - mean) * inv * gv.z + bv.z);
  o.w = f2bf((v3 - mean) * inv * gv.w + bv.w);
  *(u16x4*)&out[(size_t)row * ND + tid * 4] = o;
}

// ------- LDS-tiled transpose body (coalesced both sides) --------------------
__device__ __forceinline__ void transp_body(
    ushort (*t)[72], const float* __restrict__ in, ushort* __restrict__ out,
    int R, int C, int HB, size_t sh, size_t sl, int bid)
{
  const int tid = threadIdx.x;
  int ntx = C >> 6, nty = R >> 6;
  int tpb = ntx * nty;
  int bi = bid / tpb;
  int rem = bid - bi * tpb;
  int ty = rem / ntx, tx = rem - ty * ntx;
  int r0 = ty << 6, c0 = tx << 6;
  const float* ip = in + (size_t)bi * R * C;
  #pragma unroll
  for (int p = 0; p < 4; ++p) {
    int r = (tid >> 4) + p * 16;
    int c = (tid & 15) * 4;
    float4 v = *(const float4*)&ip[(size_t)(r0 + r) * C + c0 + c];
    t[c + 0][r] = f2bf(v.x); t[c + 1][r] = f2bf(v.y);
    t[c + 2][r] = f2bf(v.z); t[c + 3][r] = f2bf(v.w);
  }
  __syncthreads();
  ushort* op = out + (size_t)(bi / HB) * sl + (size_t)(bi % HB) * sh;
  #pragma unroll
  for (int p = 0; p < 4; ++p) {
    int c = (tid >> 4) + p * 16;
    int r = (tid & 15) * 4;
    u16x4 o = *(const u16x4*)&t[c][r];
    *(u16x4*)&op[(size_t)(c0 + c) * R + r0 + r] = o;
  }
}

// ------- all weight transposes in ONE launch (11904 blocks) -----------------
__global__ __launch_bounds__(256) void transp_all(
    const float* __restrict__ Wq, const float* __restrict__ Wk,
    const float* __restrict__ Wv, const float* __restrict__ Wp,
    const float* __restrict__ W1, const float* __restrict__ W2,
    const float* __restrict__ Wlm,
    ushort* __restrict__ qkvT, ushort* __restrict__ wpT,
    ushort* __restrict__ w1T, ushort* __restrict__ w2T,
    ushort* __restrict__ wlmT)
{
  __shared__ ushort t[64][72];
  const size_t LQKV = (size_t)2304 * ND;
  const size_t SH = (size_t)NDH * ND;
  int bid = blockIdx.x;
  if (bid < 864)        transp_body(t, Wq, qkvT,                    ND, NDH, NH, SH, LQKV, bid);
  else if (bid < 1728)  transp_body(t, Wk, qkvT + (size_t)ND*ND,    ND, NDH, NH, SH, LQKV, bid - 864);
  else if (bid < 2592)  transp_body(t, Wv, qkvT + (size_t)2*ND*ND,  ND, NDH, NH, SH, LQKV, bid - 1728);
  else if (bid < 3456)  transp_body(t, Wp, wpT, ND, ND, 1, 0, (size_t)ND * ND, bid - 2592);
  else if (bid < 6912)  transp_body(t, W1, w1T, ND, NFF, 1, 0, (size_t)ND * NFF, bid - 3456);
  else if (bid < 10368) transp_body(t, W2, w2T, NFF, ND, 1, 0, (size_t)ND * NFF, bid - 6912);
  else                  transp_body(t, Wlm, wlmT, ND, NV, 1, 0, (size_t)ND * NV, bid - 10368);
}

// ---------------- bf16 MFMA GEMM 128x128, BK=64 (m97 structure) -------------
// Used for proj / FF2 (N=768). OUT: 0 = none (RESID in-place).
template<bool BIAS, bool RELU, bool RESID, int OUT>
__global__ __launch_bounds__(256) void gemm_bt(
    const ushort* __restrict__ A, const ushort* __restrict__ Bt,
    const float* __restrict__ bias, ushort* __restrict__ xres,
    void* __restrict__ outp, void* __restrict__ outp2,
    int M, int N, int K)
{
  __shared__ ushort As[8192];   // [128][64] ushort = 16 KB
  __shared__ ushort Bs[8192];
  const int tid = threadIdx.x;
  const int lane = tid & 63;
  const int w = tid >> 6;
  const int wr = w >> 1, wc = w & 1;
  const int lg = lane >> 4, li = lane & 15;
  const int m0 = blockIdx.y * 128, n0 = blockIdx.x * 128;

  const int tr = tid >> 3;
  const int tc = ((tid & 7) ^ (tr & 7)) << 3;
  const ushort* gA = &A[(size_t)(m0 + tr) * K + tc];
  const ushort* gB = &Bt[(size_t)(n0 + tr) * K + tc];

  f32x4 acc[4][4];
  #pragma unroll
  for (int i = 0; i < 4; ++i)
    #pragma unroll
    for (int j = 0; j < 4; ++j) { f32x4 z = {0.f,0.f,0.f,0.f}; acc[i][j] = z; }

  for (int kk = 0; kk < K; kk += 64) {
    __syncthreads();
    #pragma unroll
    for (int g = 0; g < 4; ++g) {
      gload16(gA + (size_t)(g * 32) * K + kk, &As[g * 2048 + w * 512]);
      gload16(gB + (size_t)(g * 32) * K + kk, &Bs[g * 2048 + w * 512]);
    }
    __syncthreads();
    #pragma unroll
    for (int kh = 0; kh < 2; ++kh) {
      s16x8 af[4], bfr[4];
      #pragma unroll
      for (int i = 0; i < 4; ++i) {
        int ra = wr * 64 + i * 16 + li;
        int rb = wc * 64 + i * 16 + li;
        int cha = (((kh * 4 + lg) ^ (ra & 7)) << 3);
        int chb = (((kh * 4 + lg) ^ (rb & 7)) << 3);
        af[i]  = *(const s16x8*)&As[ra * 64 + cha];
        bfr[i] = *(const s16x8*)&Bs[rb * 64 + chb];
      }
      #pragma unroll
      for (int i = 0; i < 4; ++i)
        #pragma unroll
        for (int j = 0; j < 4; ++j)
          acc[i][j] = __builtin_amdgcn_mfma_f32_16x16x32_bf16(af[i], bfr[j], acc[i][j], 0, 0, 0);
    }
  }

  #pragma unroll
  for (int i = 0; i < 4; ++i) {
    #pragma unroll
    for (int j = 0; j < 4; ++j) {
      int row0 = m0 + wr * 64 + i * 16 + lg * 4;
      int col  = n0 + wc * 64 + j * 16 + li;
      float bv = BIAS ? bias[col] : 0.f;
      #pragma unroll
      for (int ii = 0; ii < 4; ++ii) {
        float val = acc[i][j][ii] + bv;
        if (RELU) val = fmaxf(val, 0.f);
        size_t off = (size_t)(row0 + ii) * N + col;
        if (RESID) { val += bf2f(xres[off]); xres[off] = f2bf(val); }
        if (OUT == 1) ((ushort*)outp)[off] = f2bf(val);
      }
    }
  }
}

// ---------------- bf16 MFMA GEMM 128x256, BK=64, 512 thr / 8 waves ----------
// Same 2-barrier choreography as gemm_bt; per-wave workload identical (64x64).
// OUT: 1 = bf16, 2 = f32 + LSE partials (outp2 = float2 pstat),
//      3 = qkv-fused (V cols (n0>=1536) -> outp2 = vT transposed store).
template<bool BIAS, bool RELU, int OUT>
__global__ __launch_bounds__(512) void gemm_wide(
    const ushort* __restrict__ A, const ushort* __restrict__ Bt,
    const float* __restrict__ bias,
    void* __restrict__ outp, void* __restrict__ outp2,
    int M, int N, int K)
{
  __shared__ ushort As[8192];    // [128][64] = 16 KB
  __shared__ ushort Bs[16384];   // [256][64] = 32 KB
  const int tid = threadIdx.x;
  const int lane = tid & 63;
  const int w = tid >> 6;            // 0..7
  const int wr = w >> 2, wc = w & 3; // 2M x 4N
  const int lg = lane >> 4, li = lane & 15;
  const int m0 = blockIdx.y * 128, n0 = blockIdx.x * 256;

  // staging: lane covers 8 rows per wave slice; row&7 == lane>>3
  const int lr = lane >> 3;
  const int lc = ((lane & 7) ^ lr) << 3;
  const ushort* gA = &A[(size_t)(m0 + w * 8 + lr) * K + lc];
  const ushort* gB = &Bt[(size_t)(n0 + w * 8 + lr) * K + lc];

  f32x4 acc[4][4];
  #pragma unroll
  for (int i = 0; i < 4; ++i)
    #pragma unroll
    for (int j = 0; j < 4; ++j) { f32x4 z = {0.f,0.f,0.f,0.f}; acc[i][j] = z; }

  for (int kk = 0; kk < K; kk += 64) {
    __syncthreads();
    #pragma unroll
    for (int g = 0; g < 2; ++g)
      gload16(gA + (size_t)(g * 64) * K + kk, &As[(g * 64 + w * 8) * 64]);
    #pragma unroll
    for (int g = 0; g < 4; ++g)
      gload16(gB + (size_t)(g * 64) * K + kk, &Bs[(g * 64 + w * 8) * 64]);
    __syncthreads();
    #pragma unroll
    for (int kh = 0; kh < 2; ++kh) {
      s16x8 af[4], bfr[4];
      #pragma unroll
      for (int i = 0; i < 4; ++i) {
        int ra = wr * 64 + i * 16 + li;
        int rb = wc * 64 + i * 16 + li;
        int cha = (((kh * 4 + lg) ^ (ra & 7)) << 3);
        int chb = (((kh * 4 + lg) ^ (rb & 7)) << 3);
        af[i]  = *(const s16x8*)&As[ra * 64 + cha];
        bfr[i] = *(const s16x8*)&Bs[rb * 64 + chb];
      }
      #pragma unroll
      for (int i = 0; i < 4; ++i)
        #pragma unroll
        for (int j = 0; j < 4; ++j)
          acc[i][j] = __builtin_amdgcn_mfma_f32_16x16x32_bf16(af[i], bfr[j], acc[i][j], 0, 0, 0);
    }
  }

  if (OUT == 2) {
    // fused f32 store + per-row LSE partials, single pass
    float2* pstat = (float2*)outp2;
    float* op = (float*)outp;
    float bvv[4];
    #pragma unroll
    for (int j = 0; j < 4; ++j)
      bvv[j] = BIAS ? bias[n0 + wc * 64 + j * 16 + li] : 0.f;
    #pragma unroll
    for (int i = 0; i < 4; ++i) {
      #pragma unroll
      for (int ii = 0; ii < 4; ++ii) {
        int row = m0 + wr * 64 + i * 16 + lg * 4 + ii;
        float v4[4];
        float mx = -1e30f;
        #pragma unroll
        for (int j = 0; j < 4; ++j) {
          float val = acc[i][j][ii] + bvv[j];
          op[(size_t)row * N + n0 + wc * 64 + j * 16 + li] = val;
          v4[j] = val; mx = fmaxf(mx, val);
        }
        #pragma unroll
        for (int d = 1; d < 16; d <<= 1) mx = fmaxf(mx, __shfl_xor(mx, d));
        float se = 0.f;
        #pragma unroll
        for (int j = 0; j < 4; ++j) se += __expf(v4[j] - mx);
        #pragma unroll
        for (int d = 1; d < 16; d <<= 1) se += __shfl_xor(se, d);
        if (li == 0) {
          float2 pv; pv.x = mx; pv.y = se;
          pstat[(size_t)row * 128 + (n0 >> 6) + wc] = pv;
        }
      }
    }
    return;
  }

  const bool isV = (OUT == 3) && (n0 >= 1536);   // qkv: n0 in {1536,1792,2048}
  #pragma unroll
  for (int i = 0; i < 4; ++i) {
    #pragma unroll
    for (int j = 0; j < 4; ++j) {
      int row0 = m0 + wr * 64 + i * 16 + lg * 4;
      int col  = n0 + wc * 64 + j * 16 + li;
      float bv = BIAS ? bias[col] : 0.f;
      if (isV) {
        int dhg = col - 1536;
        int hh = dhg >> 6, dh = dhg & 63;
        int b_ = row0 >> 10, t0 = row0 & (NT - 1);
        u16x4 o;
        o.x = f2bf(acc[i][j][0]); o.y = f2bf(acc[i][j][1]);
        o.z = f2bf(acc[i][j][2]); o.w = f2bf(acc[i][j][3]);
        *(u16x4*)&((ushort*)outp2)[((size_t)(b_ * NH + hh) * 64 + dh) * NT + t0] = o;
      } else {
        #pragma unroll
        for (int ii = 0; ii < 4; ++ii) {
          float val = acc[i][j][ii] + bv;
          if (RELU) val = fmaxf(val, 0.f);
          size_t off = (size_t)(row0 + ii) * N + col;
          ((ushort*)outp)[off] = f2bf(val);
        }
      }
    }
  }
}

// ---------------- MFMA causal flash attention, 128-row q-tiles ---------------
// qkv: [NTOK][2304] bf16 (Q/K valid); vT: [(b*NH+h)*64+dh][NT].
__global__ __launch_bounds__(256) void attn_kernel(
    const ushort* __restrict__ qkv, const ushort* __restrict__ vT,
    ushort* __restrict__ o)
{
  __shared__ ushort Ks[64 * 64];      // [key][dh], swizzled
  __shared__ ushort Vt[64 * 64];      // [dh][key], swizzled
  __shared__ ushort Ps[4][32 * 64];   // per-wave P [qrow 0..31][key], swizzled

  const int tid = threadIdx.x;
  const int lane = tid & 63;
  const int w = tid >> 6;
  const int lg = lane >> 4;
  const int li = lane & 15;

  int bid = blockIdx.x;
  const int qt = bid & 7;
  const int h = (bid >> 3) % NH;
  const int b = bid / (8 * NH);
  const int q0 = qt * 128 + w * 32;
  const size_t nbase = (size_t)b * NT;
  const int hq = h * NDH;
  const int hk = ND + h * NDH;

  s16x8 aq[2][2];
  #pragma unroll
  for (int f = 0; f < 2; ++f)
    #pragma unroll
    for (int c = 0; c < 2; ++c)
      aq[f][c] = *(const s16x8*)&qkv[(nbase + q0 + f * 16 + li) * (3 * ND) + hq + c * 32 + lg * 8];

  float m_r[2][4], l_r[2][4];
  f32x4 oacc[2][4];
  #pragma unroll
  for (int f = 0; f < 2; ++f)
    #pragma unroll
    for (int i = 0; i < 4; ++i) { m_r[f][i] = -1e30f; l_r[f][i] = 0.f; }
  #pragma unroll
  for (int f = 0; f < 2; ++f)
    #pragma unroll
    for (int n = 0; n < 4; ++n) { f32x4 z = {0.f,0.f,0.f,0.f}; oacc[f][n] = z; }

  const float scale = 0.036084391824351615f;  // 768^-0.5 (reference uses D, not DH)
  const ushort* vTb = vT + (size_t)(b * NH + h) * 64 * NT;

  const int nkc = 2 * qt + 2;
  for (int kc = 0; kc < nkc; ++kc) {
    {
      const int kr = lane >> 3;
      const int ch = lane & 7;
      #pragma unroll
      for (int g = 0; g < 2; ++g) {
        int row = g * 32 + w * 8 + kr;   // key for K, dh for Vt
        gload16(&qkv[(nbase + kc * 64 + row) * (size_t)(3 * ND) + hk + ((ch ^ (row & 7)) << 3)],
                &Ks[(g * 32 + w * 8) * 64]);
        gload16(&vTb[(size_t)row * NT + kc * 64 + ((ch ^ (row & 7)) << 3)],
                &Vt[(g * 32 + w * 8) * 64]);
      }
    }
    __syncthreads();
    if (kc * 64 <= q0 + 31) {
      f32x4 s[2][4];
      #pragma unroll
      for (int kt = 0; kt < 4; ++kt) {
        s16x8 bk[2];
        #pragma unroll
        for (int c = 0; c < 2; ++c)
          bk[c] = *(const s16x8*)&Ks[swz(kt * 16 + li, c * 32 + lg * 8)];
        #pragma unroll
        for (int f = 0; f < 2; ++f) {
          f32x4 z = {0.f,0.f,0.f,0.f}; s[f][kt] = z;
          #pragma unroll
          for (int c = 0; c < 2; ++c)
            s[f][kt] = __builtin_amdgcn_mfma_f32_16x16x32_bf16(aq[f][c], bk[c], s[f][kt], 0, 0, 0);
        }
      }
      #pragma unroll
      for (int f = 0; f < 2; ++f) {
        #pragma unroll
        for (int i = 0; i < 4; ++i) {
          int row = q0 + f * 16 + lg * 4 + i;
          float sv[4]; float mx = -1e30f;
          #pragma unroll
          for (int kt = 0; kt < 4; ++kt) {
            int key = kc * 64 + kt * 16 + li;
            float t = s[f][kt][i] * scale;
            t = (key <= row) ? t : -1e30f;
            sv[kt] = t; mx = fmaxf(mx, t);
          }
          #pragma unroll
          for (int d = 1; d < 16; d <<= 1) mx = fmaxf(mx, __shfl_xor(mx, d));
          float mnew = fmaxf(m_r[f][i], mx);
          float corr = __expf(m_r[f][i] - mnew);
          float ps = 0.f;
          #pragma unroll
          for (int kt = 0; kt < 4; ++kt) {
            float pe = __expf(sv[kt] - mnew);
            ps += pe;
            Ps[w][swz(f * 16 + lg * 4 + i, kt * 16 + li)] = f2bf(pe);
          }
          #pragma unroll
          for (int d = 1; d < 16; d <<= 1) ps += __shfl_xor(ps, d);
          l_r[f][i] = l_r[f][i] * corr + ps;
          m_r[f][i] = mnew;
          #pragma unroll
          for (int n = 0; n < 4; ++n) oacc[f][n][i] *= corr;
        }
      }
      #pragma unroll
      for (int c = 0; c < 2; ++c) {
        s16x8 ap[2], bv[4];
        #pragma unroll
        for (int f = 0; f < 2; ++f)
          ap[f] = *(const s16x8*)&Ps[w][swz(f * 16 + li, c * 32 + lg * 8)];
        #pragma unroll
        for (int n = 0; n < 4; ++n)
          bv[n] = *(const s16x8*)&Vt[swz(n * 16 + li, c * 32 + lg * 8)];
        #pragma unroll
        for (int f = 0; f < 2; ++f)
          #pragma unroll
          for (int n = 0; n < 4; ++n)
            oacc[f][n] = __builtin_amdgcn_mfma_f32_16x16x32_bf16(ap[f], bv[n], oacc[f][n], 0, 0, 0);
      }
    }
    __syncthreads();
  }
  #pragma unroll
  for (int f = 0; f < 2; ++f)
    #pragma unroll
    for (int n = 0; n < 4; ++n)
      #pragma unroll
      for (int i = 0; i < 4; ++i) {
        float val = oacc[f][n][i] / l_r[f][i];
        o[(nbase + q0 + f * 16 + lg * 4 + i) * ND + hq + n * 16 + li] = f2bf(val);
      }
}

// ---------------- loss from LSE partials (reads 8 MB, not 268 MB) -----------
__global__ __launch_bounds__(128) void loss_lse(
    const float2* __restrict__ pstat, const float* __restrict__ logits,
    const int* __restrict__ targets, float* __restrict__ rowloss)
{
  int row = blockIdx.x, tid = threadIdx.x;
  float2 p = pstat[(size_t)row * 128 + tid];
  float mx = p.x;
  #pragma unroll
  for (int d = 1; d < 64; d <<= 1) mx = fmaxf(mx, __shfl_xor(mx, d));
  __shared__ float sm[2], ss[2];
  int w = tid >> 6;
  if ((tid & 63) == 0) sm[w] = mx;
  __syncthreads();
  mx = fmaxf(sm[0], sm[1]);
  float se = p.y * __expf(p.x - mx);
  #pragma unroll
  for (int d = 1; d < 64; d <<= 1) se += __shfl_xor(se, d);
  if ((tid & 63) == 0) ss[w] = se;
  __syncthreads();
  if (tid == 0) {
    float lse = mx + __logf(ss[0] + ss[1]);
    rowloss[row] = lse - logits[(size_t)row * NV + targets[row]];
  }
}

__global__ __launch_bounds__(256) void loss_reduce(
    const float* __restrict__ rowloss, float* __restrict__ out_loss)
{
  int tid = threadIdx.x;
  float s = 0.f;
  #pragma unroll
  for (int i = 0; i < 32; ++i) s += rowloss[tid + i * 256];
  #pragma unroll
  for (int d = 1; d < 64; d <<= 1) s += __shfl_xor(s, d);
  __shared__ float red[4];
  int w = tid >> 6, lane = tid & 63;
  if (lane == 0) red[w] = s;
  __syncthreads();
  if (tid == 0) {
    float total = red[0] + red[1] + red[2] + red[3];
    out_loss[0] = total * (1.0f / NTOK);
  }
}

// ---------------- launch ----------------
extern "C" void kernel_launch(void* const* d_in, const int* in_sizes, int n_in,
                              void* d_out, int out_size, void* d_ws, size_t ws_size,
                              hipStream_t stream)
{
  const int*   idx     = (const int*)d_in[0];
  const int*   targets = (const int*)d_in[1];
  const float* tok     = (const float*)d_in[2];
  const float* pos     = (const float*)d_in[3];
  const float* ln1g    = (const float*)d_in[4];
  const float* ln1b    = (const float*)d_in[5];
  const float* Wq      = (const float*)d_in[6];
  const float* Wk      = (const float*)d_in[7];
  const float* Wv      = (const float*)d_in[8];
  const float* Wp      = (const float*)d_in[9];
  const float* bp      = (const float*)d_in[10];
  const float* ln2g    = (const float*)d_in[11];
  const float* ln2b    = (const float*)d_in[12];
  const float* W1      = (const float*)d_in[13];
  const float* b1      = (const float*)d_in[14];
  const float* W2      = (const float*)d_in[15];
  const float* b2      = (const float*)d_in[16];
  const float* lnfg    = (const float*)d_in[17];
  const float* lnfb    = (const float*)d_in[18];
  const float* Wlm     = (const float*)d_in[19];
  const float* blm     = (const float*)d_in[20];

  // d_out (f32, 268,435,460 B) doubles as scratch; all dead before final GEMM.
  char* ob = (char*)d_out;
  ushort* x    = (ushort*)ob;                               // bf16 [NTOK][ND]
  ushort* qkvb = (ushort*)(ob + 25165824);
  ushort* mid  = (ushort*)(ob + 25165824);
  ushort* qkvT = (ushort*)(ob + 75497472);                  // 6 x [2304][768]
  ushort* wpT  = (ushort*)(ob + 75497472 + 21233664);       // 6 x [768][768]
  ushort* w1T  = (ushort*)(ob + 75497472 + 28311552);       // 6 x [3072][768]
  ushort* w2T  = (ushort*)(ob + 75497472 + 56623104);       // 6 x [768][3072]
  ushort* vTb  = (ushort*)(ob + 160432128);                 // [NB*NH*64][NT] bf16, 12.6 MB
  float* logits = (float*)d_out;

  char* ws = (char*)d_ws;
  size_t off = 0;
  auto alloc = [&](size_t bytes) -> void* {
    void* p = ws + off; off += (bytes + 255) & ~(size_t)255; return p;
  };
  ushort* h    = (ushort*)alloc((size_t)NTOK * ND * 2);     // ln out / attn out
  ushort* wlmT = (ushort*)alloc((size_t)ND * NV * 2);       // read during logits GEMM
  float*  rowloss = (float*)alloc((size_t)NTOK * 4);
  float*  pstat = (float*)alloc((size_t)NTOK * 128 * 8);    // float2 [NTOK][128]

  embed_kernel<<<NTOK, 192, 0, stream>>>(idx, tok, pos, x);

  transp_all<<<11904, 256, 0, stream>>>(Wq, Wk, Wv, Wp, W1, W2, Wlm,
                                        qkvT, wpT, w1T, w2T, wlmT);

  const size_t LQKV = (size_t)2304 * ND;
  dim3 gqkv(2304 / 256, NTOK / 128);   // 9 x 64
  dim3 g768(ND / 128, NTOK / 128);     // 6 x 64
  dim3 gff(NFF / 256, NTOK / 128);     // 12 x 64
  dim3 glm(NV / 256, NTOK / 128);      // 32 x 64

  for (int l = 0; l < NL; ++l) {
    ln_kernel<<<NTOK, 192, 0, stream>>>(x, ln1g + l * ND, ln1b + l * ND, h);
    gemm_wide<false,false,3><<<gqkv, 512, 0, stream>>>(h, qkvT + l * LQKV, nullptr, qkvb, vTb, NTOK, 2304, ND);
    attn_kernel<<<NB * NH * (NT / 128), 256, 0, stream>>>(qkvb, vTb, h);
    gemm_bt<true,false,true,0><<<g768, 256, 0, stream>>>(h, wpT + (size_t)l * ND * ND, bp + l * ND, x, nullptr, nullptr, NTOK, ND, ND);
    ln_kernel<<<NTOK, 192, 0, stream>>>(x, ln2g + l * ND, ln2b + l * ND, h);
    gemm_wide<true,true,1><<<gff, 512, 0, stream>>>(h, w1T + (size_t)l * ND * NFF, b1 + (size_t)l * NFF, mid, nullptr, NTOK, NFF, ND);
    gemm_bt<true,false,true,0><<<g768, 256, 0, stream>>>(mid, w2T + (size_t)l * ND * NFF, b2 + l * ND, x, nullptr, nullptr, NTOK, ND, NFF);
  }

  ln_kernel<<<NTOK, 192, 0, stream>>>(x, lnfg, lnfb, h);
  gemm_wide<true,false,2><<<glm, 512, 0, stream>>>(h, wlmT, blm, logits, pstat, NTOK, NV, ND);

  loss_lse<<<NTOK, 128, 0, stream>>>((const float2*)pstat, logits, targets, rowloss);
  loss_reduce<<<1, 256, 0, stream>>>(rowloss, logits + (size_t)NTOK * NV);
}